// Round 9
// baseline (475.288 us; speedup 1.0000x reference)
//
#include <hip/hip_runtime.h>
#include <math.h>

// NT=64, NR=4, DK=2, KU=8, BR=16, BATCH=256
// channel:    [B][64][4][16][16] f32 (last dim: 8 re, 8 im)
// prediction: [B][2560] = U[4][2][16][16] ++ W[2][2][16][8]
// out:        [B][64][2][8][2] f32
//
// R17 = R15 (88us: R8 quad + 8-pivot panel GJ) + two changes:
//  (a) direct complex accumulation: acc[i][j] (2 floats) instead of
//      accA/accB (4 floats). C.re += xx+yy+zz+ww, C.im += yx-xy+wz-zw
//      -- algebraically identical to the old combine, saves 32 VGPRs.
//  (b) channel register prefetch: issue fi+1's 4 float4 loads BEFORE
//      quadf(fi); butterfly consumes them AFTER the quad burst. The
//      1KB-strided gather (64 lines/wave/instr) latency hides under
//      ~2us of fmaf instead of serializing each interval. Only 16 regs
//      live across quad (R16 kept whole butterfly contexts -> spill).
// Peak demand ~108 < the 128-VGPR cap empirically enforced for
// 512-thread blocks (R16: compiled to 128 + 467MB scratch).

#define SAUG 84   // float2 stride of Aug rows
#define STP  65   // float4 stride of paired TtP/HtP rows

namespace {
union alignas(16) ShU {
    struct { float4 TtP[2][2][8][STP]; float4 HtP[2][2][8][STP]; } p1; // 66560 B
    float2 Aug[64][SAUG];                                              // 43008 B
};
union alignas(16) ShV {
    struct { float2 U[4 * 258]; float W[512]; } in;                    // 10304 B
    float2 xout[64][17];                                               // 8704 B
};
struct Ch { float4 a, b, c, d; };
}

__device__ __forceinline__ float2 cmul(float2 x, float2 y) {
    return make_float2(x.x * y.x - x.y * y.y, x.x * y.y + x.y * y.x);
}

__global__ __launch_bounds__(512, 1)
void uw2v_kernel(const float* __restrict__ channel,
                 const float* __restrict__ prediction,
                 float2* __restrict__ out)
{
    __shared__ ShU sh;
    __shared__ ShV sv;
    __shared__ alignas(16) float2 pivR[2][8][80];  // chunk pivot rows (dbuf)
    __shared__ float2 pivI[2][8];                  // chunk inverse pivots
    __shared__ float2 redbuf[8];
    __shared__ float  fred[8];

    const int b   = blockIdx.x;
    const int tid = threadIdx.x;
    const int wv  = tid >> 6;
    const float* pred = prediction + (size_t)b * 2560;
    const float* chan = channel + (size_t)b * 65536;

    // ---- load U (re/im merged, padded per-r stride) and W ----
    #pragma unroll
    for (int i = 0; i < 2; ++i) {
        int m = tid + i * 512;                       // [r][d][f][k]
        int r = m >> 8, d = (m >> 7) & 1, f = (m >> 3) & 15, k = m & 7;
        const float* src = pred + (((r * 2 + d) * 16 + f) << 4);
        sv.in.U[r * 258 + ((d * 16 + f) << 3) + k] = make_float2(src[k], src[k + 8]);
    }
    sv.in.W[tid] = pred[2048 + tid];
    __syncthreads();

    const int half = tid >> 8;
    const int lt   = tid & 255;
    const int t4 = lt >> 2, r4 = lt & 3;
    const int a  = lt >> 4, bb = lt & 15;
    const int bit0 = r4 & 1, bit1 = (r4 >> 1) & 1;
    const int kkb  = 4 * bit0 + 2 * bit1;            // owned k-slice base (even)
    const int mpb  = kkb >> 1;                       // owned m-pair row (0..3)
    const int fbase = half << 3;
    const int tr_r = lt >> 5, tr_d = (lt >> 4) & 1, tr_e = (lt >> 3) & 1, tr_k = lt & 7;

    // direct complex accumulators (32 regs)
    float2 acc[4][4];
    #pragma unroll
    for (int i = 0; i < 4; ++i)
        #pragma unroll
        for (int j = 0; j < 4; ++j)
            acc[i][j] = make_float2(0.f, 0.f);
    float2 huw[4] = {make_float2(0,0), make_float2(0,0), make_float2(0,0), make_float2(0,0)};
    float2 tracc  = make_float2(0.f, 0.f);

    const float* hbase = chan + ((t4 * 4 + r4) << 8) + (fbase << 4);

    // channel register prefetch (16 regs)
    auto ldch = [&](int fi) {
        Ch r;
        r.a = *(const float4*)(hbase + (fi << 4) + 0);
        r.b = *(const float4*)(hbase + (fi << 4) + 4);
        r.c = *(const float4*)(hbase + (fi << 4) + 8);
        r.d = *(const float4*)(hbase + (fi << 4) + 12);
        return r;
    };

    // butterfly + T/H staging for subband fi -> buffer p (compile-time p)
    auto stage = [&](int fi, int p, Ch ch) {
        const int f = fbase + fi;
        const float4* U0p = (const float4*)&sv.in.U[r4 * 258 + (f << 3)];        // d=0
        const float4* U1p = (const float4*)&sv.in.U[r4 * 258 + ((16 + f) << 3)]; // d=1
        const float4 u0q0 = U0p[0], u0q1 = U0p[1], u0q2 = U0p[2], u0q3 = U0p[3];
        const float4 u1q0 = U1p[0], u1q1 = U1p[1], u1q2 = U1p[2], u1q3 = U1p[3];

        // partials: val0[k] = conj(H)*U (d=0, m=k), val1[k] (d=1, m=8+k)
        float2 val0[8], val1[8];
        #define MK2(K, HR, HI, U0R, U0I, U1R, U1I) \
            val0[K] = make_float2((HR)*(U0R) + (HI)*(U0I), (HR)*(U0I) - (HI)*(U0R)); \
            val1[K] = make_float2((HR)*(U1R) + (HI)*(U1I), (HR)*(U1I) - (HI)*(U1R));
        MK2(0, ch.a.x, ch.c.x, u0q0.x, u0q0.y, u1q0.x, u1q0.y)
        MK2(1, ch.a.y, ch.c.y, u0q0.z, u0q0.w, u1q0.z, u1q0.w)
        MK2(2, ch.a.z, ch.c.z, u0q1.x, u0q1.y, u1q1.x, u1q1.y)
        MK2(3, ch.a.w, ch.c.w, u0q1.z, u0q1.w, u1q1.z, u1q1.w)
        MK2(4, ch.b.x, ch.d.x, u0q2.x, u0q2.y, u1q2.x, u1q2.y)
        MK2(5, ch.b.y, ch.d.y, u0q2.z, u0q2.w, u1q2.z, u1q2.w)
        MK2(6, ch.b.z, ch.d.z, u0q3.x, u0q3.y, u1q3.x, u1q3.y)
        MK2(7, ch.b.w, ch.d.w, u0q3.z, u0q3.w, u1q3.z, u1q3.w)
        #undef MK2

        // stage 1 (xor 1): keep k in {4*bit0 .. 4*bit0+3}
        float2 s1d0[4], s1d1[4];
        #pragma unroll
        for (int q = 0; q < 4; ++q) {
            float2 k0 = bit0 ? val0[4 + q] : val0[q];
            float2 n0 = bit0 ? val0[q]     : val0[4 + q];
            float2 k1 = bit0 ? val1[4 + q] : val1[q];
            float2 n1 = bit0 ? val1[q]     : val1[4 + q];
            n0.x = __shfl_xor(n0.x, 1); n0.y = __shfl_xor(n0.y, 1);
            n1.x = __shfl_xor(n1.x, 1); n1.y = __shfl_xor(n1.y, 1);
            s1d0[q] = make_float2(k0.x + n0.x, k0.y + n0.y);
            s1d1[q] = make_float2(k1.x + n1.x, k1.y + n1.y);
        }
        // stage 2 (xor 2): keep q in {2*bit1, 2*bit1+1} -> hh[kkb+jj]
        float2 h0[2], h1[2];
        #pragma unroll
        for (int jj = 0; jj < 2; ++jj) {
            float2 k0 = bit1 ? s1d0[2 + jj] : s1d0[jj];
            float2 n0 = bit1 ? s1d0[jj]     : s1d0[2 + jj];
            float2 k1 = bit1 ? s1d1[2 + jj] : s1d1[jj];
            float2 n1 = bit1 ? s1d1[jj]     : s1d1[2 + jj];
            n0.x = __shfl_xor(n0.x, 2); n0.y = __shfl_xor(n0.y, 2);
            n1.x = __shfl_xor(n1.x, 2); n1.y = __shfl_xor(n1.y, 2);
            h0[jj] = make_float2(k0.x + n0.x, k0.y + n0.y);
            h1[jj] = make_float2(k1.x + n1.x, k1.y + n1.y);
        }

        // tr_UWU partial (128 lanes per half; wave-uniform branch)
        if (lt < 128) {
            float w   = sv.in.W[((tr_d * 2 + tr_e) * 16 + f) * 8 + tr_k];
            float2 u1 = sv.in.U[tr_r * 258 + ((tr_d * 16 + f) << 3) + tr_k];
            float2 u2 = sv.in.U[tr_r * 258 + ((tr_e * 16 + f) << 3) + tr_k];
            tracc.x += w * (u1.x * u2.x + u1.y * u2.y);
            tracc.y += w * (u1.y * u2.x - u1.x * u2.y);
        }

        // T pairs + H pairs (b128 writes, m-pair rows)
        #pragma unroll
        for (int e = 0; e < 2; ++e) {
            float w0a = sv.in.W[(e * 16 + f) * 8 + kkb];
            float w0b = sv.in.W[(e * 16 + f) * 8 + kkb + 1];
            float w1a = sv.in.W[((2 + e) * 16 + f) * 8 + kkb];
            float w1b = sv.in.W[((2 + e) * 16 + f) * 8 + kkb + 1];
            float2 tva = make_float2(h0[0].x * w0a + h1[0].x * w1a,
                                     h0[0].y * w0a + h1[0].y * w1a);
            float2 tvb = make_float2(h0[1].x * w0b + h1[1].x * w1b,
                                     h0[1].y * w0b + h1[1].y * w1b);
            sh.p1.TtP[p][half][e * 4 + mpb][t4] = make_float4(tva.x, tva.y, tvb.x, tvb.y);
            huw[e * 2 + 0].x += tva.x; huw[e * 2 + 0].y += tva.y;
            huw[e * 2 + 1].x += tvb.x; huw[e * 2 + 1].y += tvb.y;
        }
        sh.p1.HtP[p][half][mpb][t4]     = make_float4(h0[0].x, h0[0].y, h0[1].x, h0[1].y);
        sh.p1.HtP[p][half][4 + mpb][t4] = make_float4(h1[0].x, h1[0].y, h1[1].x, h1[1].y);
    };

    // quad accumulation from buffer p (compile-time p), direct complex form
    auto quadf = [&](int p) {
        #pragma unroll
        for (int mp = 0; mp < 8; ++mp) {
            float4 tq[4], hq[4];
            #pragma unroll
            for (int i = 0; i < 4; ++i) tq[i] = sh.p1.TtP[p][half][mp][a + 16 * i];
            #pragma unroll
            for (int j = 0; j < 4; ++j) hq[j] = sh.p1.HtP[p][half][mp][bb + 16 * j];
            #pragma unroll
            for (int i = 0; i < 4; ++i)
                #pragma unroll
                for (int j = 0; j < 4; ++j) {
                    float2 v = acc[i][j];
                    v.x = fmaf(tq[i].x, hq[j].x, v.x);
                    v.x = fmaf(tq[i].y, hq[j].y, v.x);
                    v.x = fmaf(tq[i].z, hq[j].z, v.x);
                    v.x = fmaf(tq[i].w, hq[j].w, v.x);
                    v.y = fmaf(tq[i].y, hq[j].x, v.y);
                    v.y = fmaf(-tq[i].x, hq[j].y, v.y);
                    v.y = fmaf(tq[i].w, hq[j].z, v.y);
                    v.y = fmaf(-tq[i].z, hq[j].w, v.y);
                    acc[i][j] = v;
                }
        }
    };

    // pipeline: ld(fi+1) -> quad(fi) -> butterfly+write(fi+1) -> barrier
    {
        Ch c0 = ldch(0);
        stage(0, 0, c0);
    }
    __syncthreads();
    #pragma unroll 1
    for (int it = 0; it < 3; ++it) {
        const int fe = it << 1;
        Ch n1 = ldch(fe + 1);
        quadf(0);
        stage(fe + 1, 1, n1);
        __syncthreads();
        Ch n2 = ldch(fe + 2);
        quadf(1);
        stage(fe + 2, 0, n2);
        __syncthreads();
    }
    {
        Ch n7 = ldch(7);
        quadf(0);
        stage(7, 1, n7);
    }
    __syncthreads();
    quadf(1);

    // ---- tr_UWU block reduction ----
    #pragma unroll
    for (int off = 32; off; off >>= 1) {
        tracc.x += __shfl_xor(tracc.x, off);
        tracc.y += __shfl_xor(tracc.y, off);
    }
    if ((tid & 63) == 0) redbuf[wv] = tracc;
    __syncthreads();
    float2 trv = make_float2(0.f, 0.f);
    #pragma unroll
    for (int w = 0; w < 8; ++w) { trv.x += redbuf[w].x; trv.y += redbuf[w].y; }
    trv.x *= 0.1f; trv.y *= 0.1f;

    // ---- merge halves into Aug = [quad + trv*I | HUW] ----
    if (half == 0) {
        #pragma unroll
        for (int i = 0; i < 4; ++i)
            #pragma unroll
            for (int j = 0; j < 4; ++j) {
                float2 v = acc[i][j];
                int row = a + 16 * i, col = bb + 16 * j;
                if (row == col) { v.x += trv.x; v.y += trv.y; }
                sh.Aug[row][col] = v;
            }
        #pragma unroll
        for (int e = 0; e < 2; ++e)
            #pragma unroll
            for (int jj = 0; jj < 2; ++jj)
                sh.Aug[t4][64 + e * 8 + kkb + jj] = huw[e * 2 + jj];
    }
    __syncthreads();
    if (half == 1) {
        #pragma unroll
        for (int i = 0; i < 4; ++i)
            #pragma unroll
            for (int j = 0; j < 4; ++j) {
                int row = a + 16 * i, col = bb + 16 * j;
                float2 v = sh.Aug[row][col];
                v.x += acc[i][j].x;
                v.y += acc[i][j].y;
                sh.Aug[row][col] = v;
            }
        #pragma unroll
        for (int e = 0; e < 2; ++e)
            #pragma unroll
            for (int jj = 0; jj < 2; ++jj) {
                int col = 64 + e * 8 + kkb + jj;
                float2 v = sh.Aug[t4][col];
                v.x += huw[e * 2 + jj].x; v.y += huw[e * 2 + jj].y;
                sh.Aug[t4][col] = v;
            }
    }
    __syncthreads();

    // ---- panel Gauss-Jordan: 8 chunks of 8 pivots, wave-local cascades ----
    const int gi = tid >> 3, gc = tid & 7;           // row 0..63, col-slice 0..7
    const int cb = 10 * gc;                          // 10 cols per thread
    const int lanebase = (tid & 63) & 56;            // my row's base lane

    float2 xr[10];
    {
        const float4* rp = (const float4*)&sh.Aug[gi][cb];
        float4 q0 = rp[0], q1 = rp[1], q2 = rp[2], q3 = rp[3], q4 = rp[4];
        xr[0] = make_float2(q0.x, q0.y); xr[1] = make_float2(q0.z, q0.w);
        xr[2] = make_float2(q1.x, q1.y); xr[3] = make_float2(q1.z, q1.w);
        xr[4] = make_float2(q2.x, q2.y); xr[5] = make_float2(q2.z, q2.w);
        xr[6] = make_float2(q3.x, q3.y); xr[7] = make_float2(q3.z, q3.w);
        xr[8] = make_float2(q4.x, q4.y); xr[9] = make_float2(q4.z, q4.w);
    }

    float2 myipv = make_float2(0.f, 0.f);

    // wave-local cascade: in-panel GJ on my wave's 8 rows, publish to buf nb
    auto cascade = [&](int chunk, int nb) {
        #pragma unroll
        for (int p = 0; p < 8; ++p) {
            const int col = 8 * chunk + p;
            const int cs  = col / 10;                // owning col-slice
            float2 cand = make_float2(0.f, 0.f);
            #pragma unroll
            for (int c = 0; c < 10; ++c)
                if (cb + c == col) cand = xr[c];
            float2 z, Lv;
            z.x  = __shfl(cand.x, p * 8 + cs);
            z.y  = __shfl(cand.y, p * 8 + cs);
            Lv.x = __shfl(cand.x, lanebase + cs);
            Lv.y = __shfl(cand.y, lanebase + cs);
            float  zi  = 1.0f / (z.x * z.x + z.y * z.y);
            float2 ipv = make_float2(z.x * zi, -z.y * zi);
            const bool isPiv = (gi == col);
            if (isPiv) myipv = ipv;
            float2 pr[10];
            #pragma unroll
            for (int c = 0; c < 10; ++c) {
                pr[c].x = __shfl(xr[c].x, p * 8 + gc);
                pr[c].y = __shfl(xr[c].y, p * 8 + gc);
            }
            if (!isPiv) {
                float2 L = cmul(Lv, ipv);
                #pragma unroll
                for (int c = 0; c < 10; ++c) {
                    xr[c].x -= L.x * pr[c].x - L.y * pr[c].y;
                    xr[c].y -= L.x * pr[c].y + L.y * pr[c].x;
                }
            }
        }
        // publish raw pivot rows + inverse pivots
        const int prw = gi & 7;
        float4* wp = (float4*)&pivR[nb][prw][cb];
        wp[0] = make_float4(xr[0].x, xr[0].y, xr[1].x, xr[1].y);
        wp[1] = make_float4(xr[2].x, xr[2].y, xr[3].x, xr[3].y);
        wp[2] = make_float4(xr[4].x, xr[4].y, xr[5].x, xr[5].y);
        wp[3] = make_float4(xr[6].x, xr[6].y, xr[7].x, xr[7].y);
        wp[4] = make_float4(xr[8].x, xr[8].y, xr[9].x, xr[9].y);
        if (gc == 0) pivI[nb][prw] = myipv;
    };

    // eliminate the 8 published pivots of `chunk` (buf bf) from my row.
    auto eliminate = [&](int chunk, int bf) {
        #pragma unroll
        for (int p = 0; p < 8; ++p) {
            const int col = 8 * chunk + p;
            float2 cand = make_float2(0.f, 0.f);
            #pragma unroll
            for (int c = 0; c < 10; ++c)
                if (cb + c == col) cand = xr[c];
            float2 Lv;
            Lv.x = __shfl(cand.x, lanebase + col / 10);
            Lv.y = __shfl(cand.y, lanebase + col / 10);
            float2 ipv = pivI[bf][p];
            float2 L = cmul(Lv, ipv);
            const float4* pp = (const float4*)&pivR[bf][p][cb];
            float4 p0 = pp[0], p1 = pp[1], p2 = pp[2], p3 = pp[3], p4 = pp[4];
            float2 pr[10];
            pr[0] = make_float2(p0.x, p0.y); pr[1] = make_float2(p0.z, p0.w);
            pr[2] = make_float2(p1.x, p1.y); pr[3] = make_float2(p1.z, p1.w);
            pr[4] = make_float2(p2.x, p2.y); pr[5] = make_float2(p2.z, p2.w);
            pr[6] = make_float2(p3.x, p3.y); pr[7] = make_float2(p3.z, p3.w);
            pr[8] = make_float2(p4.x, p4.y); pr[9] = make_float2(p4.z, p4.w);
            #pragma unroll
            for (int c = 0; c < 10; ++c) {
                xr[c].x -= L.x * pr[c].x - L.y * pr[c].y;
                xr[c].y -= L.x * pr[c].y + L.y * pr[c].x;
            }
        }
    };

    int cur = 0;
    if (wv == 0) cascade(0, 0);
    __syncthreads();

    #pragma unroll 1
    for (int c = 0; c < 8; ++c) {
        if (wv != c) {
            eliminate(c, cur);
            if (wv == c + 1) cascade(c + 1, cur ^ 1);
        }
        __syncthreads();
        cur ^= 1;
    }

    // ---- extract solution (cols 64..79), normalize, write ----
    float ss = 0.f;
    if (gc == 6) {
        #pragma unroll
        for (int c = 4; c < 10; ++c) {
            float2 xv = cmul(xr[c], myipv);
            ss += xv.x * xv.x + xv.y * xv.y;
            sv.xout[gi][c - 4] = xv;
        }
    } else if (gc == 7) {
        #pragma unroll
        for (int c = 0; c < 10; ++c) {
            float2 xv = cmul(xr[c], myipv);
            ss += xv.x * xv.x + xv.y * xv.y;
            sv.xout[gi][6 + c] = xv;
        }
    }
    #pragma unroll
    for (int off = 32; off; off >>= 1) ss += __shfl_xor(ss, off);
    if ((tid & 63) == 0) fred[wv] = ss;
    __syncthreads();
    float total = 0.f;
    #pragma unroll
    for (int w = 0; w < 8; ++w) total += fred[w];
    float invn = rsqrtf(total);
    #pragma unroll
    for (int q = 0; q < 2; ++q) {
        int m = tid + q * 512;
        float2 v = sv.xout[m >> 4][m & 15];
        out[(size_t)b * 1024 + m] = make_float2(v.x * invn, v.y * invn);
    }
}

extern "C" void kernel_launch(void* const* d_in, const int* in_sizes, int n_in,
                              void* d_out, int out_size, void* d_ws, size_t ws_size,
                              hipStream_t stream) {
    const float* channel    = (const float*)d_in[0];
    const float* prediction = (const float*)d_in[1];
    int batch = in_sizes[0] / 65536;   // 256
    uw2v_kernel<<<dim3(batch), dim3(512), 0, stream>>>(channel, prediction,
                                                       (float2*)d_out);
}

// Round 10
// 166.922 us; speedup vs baseline: 2.8474x; 2.8474x over previous
//
#include <hip/hip_runtime.h>
#include <math.h>

// NT=64, NR=4, DK=2, KU=8, BR=16, BATCH=256
// channel:    [B][64][4][16][16] f32 (last dim: 8 re, 8 im)
// prediction: [B][2560] = U[4][2][16][16] ++ W[2][2][16][8]
// out:        [B][64][2][8][2] f32
//
// R18 = R15 (88us: R8 quad + 8-pivot panel GJ) + zero-register channel
// prefetch via global_load_lds:
//  - per fi, 4x global_load_lds(16B) stage the next subband's gather into
//    a per-wave LDS buffer chBuf[2][wv][4][64]; butterfly reads it from
//    LDS. No registers live across the quad burst (R16/R17 both spilled
//    >400MB trying to carry prefetch state in VGPRs past the 128 cap).
//  - quad-loop barriers become raw s_barrier + explicit lgkmcnt(0) (T/H
//    tiles are DS-only) so the in-flight global_load_lds for fi+1 is NOT
//    drained at the barrier (__syncthreads emits vmcnt(0)). The only
//    vmcnt(0) sits at the top of stage(fi), where L(fi) had a full
//    interval (barrier + quad + stage tail) to land.
//  - chBuf is per-wave private -> no cross-wave hazard; T/H WAR covered
//    by the existing double buffer + one barrier per fi (same count).
// accA/accB split accumulators kept (pk-fma pairing). GJ/epilogue: R15.

#define SAUG 84   // float2 stride of Aug rows
#define STP  65   // float4 stride of paired TtP/HtP rows

namespace {
union alignas(16) ShU {
    struct { float4 TtP[2][2][8][STP]; float4 HtP[2][2][8][STP]; } p1; // 66560 B
    float2 Aug[64][SAUG];                                              // 43008 B
};
union alignas(16) ShV {
    struct { float2 U[4 * 258]; float W[512]; } in;                    // 10304 B
    float2 xout[64][17];                                               // 8704 B
};
union alignas(16) ShC {
    float4 chBuf[2][8][4][64];                                         // 65536 B
    struct { float2 pivR[2][8][80]; float2 pivI[2][8]; } gj;           // 10368 B
};
}

__device__ __forceinline__ float2 cmul(float2 x, float2 y) {
    return make_float2(x.x * y.x - x.y * y.y, x.x * y.y + x.y * y.x);
}

__global__ __launch_bounds__(512, 1)
void uw2v_kernel(const float* __restrict__ channel,
                 const float* __restrict__ prediction,
                 float2* __restrict__ out)
{
    __shared__ ShU sh;
    __shared__ ShV sv;
    __shared__ ShC shc;
    __shared__ float2 redbuf[8];
    __shared__ float  fred[8];

    const int b   = blockIdx.x;
    const int tid = threadIdx.x;
    const int wv  = tid >> 6;
    const int lane = tid & 63;
    const float* pred = prediction + (size_t)b * 2560;
    const float* chan = channel + (size_t)b * 65536;

    // ---- load U (re/im merged, padded per-r stride) and W ----
    #pragma unroll
    for (int i = 0; i < 2; ++i) {
        int m = tid + i * 512;                       // [r][d][f][k]
        int r = m >> 8, d = (m >> 7) & 1, f = (m >> 3) & 15, k = m & 7;
        const float* src = pred + (((r * 2 + d) * 16 + f) << 4);
        sv.in.U[r * 258 + ((d * 16 + f) << 3) + k] = make_float2(src[k], src[k + 8]);
    }
    sv.in.W[tid] = pred[2048 + tid];
    __syncthreads();

    const int half = tid >> 8;
    const int lt   = tid & 255;
    const int t4 = lt >> 2, r4 = lt & 3;
    const int a  = lt >> 4, bb = lt & 15;
    const int bit0 = r4 & 1, bit1 = (r4 >> 1) & 1;
    const int kkb  = 4 * bit0 + 2 * bit1;            // owned k-slice base (even)
    const int mpb  = kkb >> 1;                       // owned m-pair row (0..3)
    const int fbase = half << 3;
    const int tr_r = lt >> 5, tr_d = (lt >> 4) & 1, tr_e = (lt >> 3) & 1, tr_k = lt & 7;

    // split accumulators: accA = sum t_re*h, accB = sum t_im*h (h = (re,im))
    float2 accA[4][4], accB[4][4];
    #pragma unroll
    for (int i = 0; i < 4; ++i)
        #pragma unroll
        for (int j = 0; j < 4; ++j) {
            accA[i][j] = make_float2(0.f, 0.f);
            accB[i][j] = make_float2(0.f, 0.f);
        }
    float2 huw[4] = {make_float2(0,0), make_float2(0,0), make_float2(0,0), make_float2(0,0)};
    float2 tracc  = make_float2(0.f, 0.f);

    const float* hbase = chan + ((t4 * 4 + r4) << 8) + (fbase << 4);

    // issue the 4x16B gather for subband fi into chBuf[n] (per-wave region;
    // dest = wave-uniform base, HW adds lane*16)
    auto issueL = [&](int fi, int n) {
        #pragma unroll
        for (int k = 0; k < 4; ++k) {
            const float* g = hbase + (fi << 4) + (k << 2);
            __builtin_amdgcn_global_load_lds(
                (const __attribute__((address_space(1))) void*)g,
                (__attribute__((address_space(3))) void*)&shc.chBuf[n][wv][k][0],
                16, 0, 0);
        }
    };

    // butterfly + T/H staging for subband fi (channel from chBuf[c]) -> buf p
    auto stage = [&](int fi, int c, int p) {
        const int f = fbase + fi;
        // L(fi) is the only outstanding vmem here; wait it explicitly.
        asm volatile("s_waitcnt vmcnt(0)" ::: "memory");
        __builtin_amdgcn_sched_barrier(0);
        const float4 ca = shc.chBuf[c][wv][0][lane];
        const float4 cb = shc.chBuf[c][wv][1][lane];
        const float4 ci = shc.chBuf[c][wv][2][lane];
        const float4 cd = shc.chBuf[c][wv][3][lane];

        const float4* U0p = (const float4*)&sv.in.U[r4 * 258 + (f << 3)];        // d=0
        const float4* U1p = (const float4*)&sv.in.U[r4 * 258 + ((16 + f) << 3)]; // d=1
        const float4 u0q0 = U0p[0], u0q1 = U0p[1], u0q2 = U0p[2], u0q3 = U0p[3];
        const float4 u1q0 = U1p[0], u1q1 = U1p[1], u1q2 = U1p[2], u1q3 = U1p[3];

        // partials: val0[k] = conj(H)*U (d=0, m=k), val1[k] (d=1, m=8+k)
        float2 val0[8], val1[8];
        #define MK2(K, HR, HI, U0R, U0I, U1R, U1I) \
            val0[K] = make_float2((HR)*(U0R) + (HI)*(U0I), (HR)*(U0I) - (HI)*(U0R)); \
            val1[K] = make_float2((HR)*(U1R) + (HI)*(U1I), (HR)*(U1I) - (HI)*(U1R));
        MK2(0, ca.x, ci.x, u0q0.x, u0q0.y, u1q0.x, u1q0.y)
        MK2(1, ca.y, ci.y, u0q0.z, u0q0.w, u1q0.z, u1q0.w)
        MK2(2, ca.z, ci.z, u0q1.x, u0q1.y, u1q1.x, u1q1.y)
        MK2(3, ca.w, ci.w, u0q1.z, u0q1.w, u1q1.z, u1q1.w)
        MK2(4, cb.x, cd.x, u0q2.x, u0q2.y, u1q2.x, u1q2.y)
        MK2(5, cb.y, cd.y, u0q2.z, u0q2.w, u1q2.z, u1q2.w)
        MK2(6, cb.z, cd.z, u0q3.x, u0q3.y, u1q3.x, u1q3.y)
        MK2(7, cb.w, cd.w, u0q3.z, u0q3.w, u1q3.z, u1q3.w)
        #undef MK2

        // stage 1 (xor 1): keep k in {4*bit0 .. 4*bit0+3}
        float2 s1d0[4], s1d1[4];
        #pragma unroll
        for (int q = 0; q < 4; ++q) {
            float2 k0 = bit0 ? val0[4 + q] : val0[q];
            float2 n0 = bit0 ? val0[q]     : val0[4 + q];
            float2 k1 = bit0 ? val1[4 + q] : val1[q];
            float2 n1 = bit0 ? val1[q]     : val1[4 + q];
            n0.x = __shfl_xor(n0.x, 1); n0.y = __shfl_xor(n0.y, 1);
            n1.x = __shfl_xor(n1.x, 1); n1.y = __shfl_xor(n1.y, 1);
            s1d0[q] = make_float2(k0.x + n0.x, k0.y + n0.y);
            s1d1[q] = make_float2(k1.x + n1.x, k1.y + n1.y);
        }
        // stage 2 (xor 2): keep q in {2*bit1, 2*bit1+1} -> hh[kkb+jj]
        float2 h0[2], h1[2];
        #pragma unroll
        for (int jj = 0; jj < 2; ++jj) {
            float2 k0 = bit1 ? s1d0[2 + jj] : s1d0[jj];
            float2 n0 = bit1 ? s1d0[jj]     : s1d0[2 + jj];
            float2 k1 = bit1 ? s1d1[2 + jj] : s1d1[jj];
            float2 n1 = bit1 ? s1d1[jj]     : s1d1[2 + jj];
            n0.x = __shfl_xor(n0.x, 2); n0.y = __shfl_xor(n0.y, 2);
            n1.x = __shfl_xor(n1.x, 2); n1.y = __shfl_xor(n1.y, 2);
            h0[jj] = make_float2(k0.x + n0.x, k0.y + n0.y);
            h1[jj] = make_float2(k1.x + n1.x, k1.y + n1.y);
        }

        // tr_UWU partial (128 lanes per half; wave-uniform branch)
        if (lt < 128) {
            float w   = sv.in.W[((tr_d * 2 + tr_e) * 16 + f) * 8 + tr_k];
            float2 u1 = sv.in.U[tr_r * 258 + ((tr_d * 16 + f) << 3) + tr_k];
            float2 u2 = sv.in.U[tr_r * 258 + ((tr_e * 16 + f) << 3) + tr_k];
            tracc.x += w * (u1.x * u2.x + u1.y * u2.y);
            tracc.y += w * (u1.y * u2.x - u1.x * u2.y);
        }

        // T pairs + H pairs (b128 writes, m-pair rows)
        #pragma unroll
        for (int e = 0; e < 2; ++e) {
            float w0a = sv.in.W[(e * 16 + f) * 8 + kkb];
            float w0b = sv.in.W[(e * 16 + f) * 8 + kkb + 1];
            float w1a = sv.in.W[((2 + e) * 16 + f) * 8 + kkb];
            float w1b = sv.in.W[((2 + e) * 16 + f) * 8 + kkb + 1];
            float2 tva = make_float2(h0[0].x * w0a + h1[0].x * w1a,
                                     h0[0].y * w0a + h1[0].y * w1a);
            float2 tvb = make_float2(h0[1].x * w0b + h1[1].x * w1b,
                                     h0[1].y * w0b + h1[1].y * w1b);
            sh.p1.TtP[p][half][e * 4 + mpb][t4] = make_float4(tva.x, tva.y, tvb.x, tvb.y);
            huw[e * 2 + 0].x += tva.x; huw[e * 2 + 0].y += tva.y;
            huw[e * 2 + 1].x += tvb.x; huw[e * 2 + 1].y += tvb.y;
        }
        sh.p1.HtP[p][half][mpb][t4]     = make_float4(h0[0].x, h0[0].y, h0[1].x, h0[1].y);
        sh.p1.HtP[p][half][4 + mpb][t4] = make_float4(h1[0].x, h1[0].y, h1[1].x, h1[1].y);
    };

    // quad accumulation from buffer p
    auto quadf = [&](int p) {
        #pragma unroll
        for (int mp = 0; mp < 8; ++mp) {
            float4 tq[4], hq[4];
            #pragma unroll
            for (int i = 0; i < 4; ++i) tq[i] = sh.p1.TtP[p][half][mp][a + 16 * i];
            #pragma unroll
            for (int j = 0; j < 4; ++j) hq[j] = sh.p1.HtP[p][half][mp][bb + 16 * j];
            #pragma unroll
            for (int i = 0; i < 4; ++i)
                #pragma unroll
                for (int j = 0; j < 4; ++j) {
                    float2 va = accA[i][j], vb = accB[i][j];
                    va.x = fmaf(tq[i].x, hq[j].x, va.x);
                    va.y = fmaf(tq[i].x, hq[j].y, va.y);
                    vb.x = fmaf(tq[i].y, hq[j].x, vb.x);
                    vb.y = fmaf(tq[i].y, hq[j].y, vb.y);
                    va.x = fmaf(tq[i].z, hq[j].z, va.x);
                    va.y = fmaf(tq[i].z, hq[j].w, va.y);
                    vb.x = fmaf(tq[i].w, hq[j].z, vb.x);
                    vb.y = fmaf(tq[i].w, hq[j].w, vb.y);
                    accA[i][j] = va; accB[i][j] = vb;
                }
        }
    };

    // raw barrier: lgkm drain (T/H DS writes) but NO vmcnt drain, so the
    // in-flight global_load_lds for fi+1 survives the barrier.
    auto rbar = [&]() {
        asm volatile("s_waitcnt lgkmcnt(0)" ::: "memory");
        __builtin_amdgcn_s_barrier();
        asm volatile("" ::: "memory");
    };

    // quad loop: vmcnt(0) -> stage(fi) -> issue L(fi+1) -> rbar -> quad(fi)
    issueL(0, 0);
    #pragma unroll 1
    for (int fi = 0; fi < 8; ++fi) {
        const int p = fi & 1;
        stage(fi, p, p);
        if (fi < 7) issueL(fi + 1, p ^ 1);
        rbar();
        quadf(p);
        // WAR on T/H buf p resolved by next interval's rbar (dbuf covers fi+1)
    }

    // ---- tr_UWU block reduction ----
    #pragma unroll
    for (int off = 32; off; off >>= 1) {
        tracc.x += __shfl_xor(tracc.x, off);
        tracc.y += __shfl_xor(tracc.y, off);
    }
    if ((tid & 63) == 0) redbuf[wv] = tracc;
    __syncthreads();
    float2 trv = make_float2(0.f, 0.f);
    #pragma unroll
    for (int w = 0; w < 8; ++w) { trv.x += redbuf[w].x; trv.y += redbuf[w].y; }
    trv.x *= 0.1f; trv.y *= 0.1f;

    // ---- merge halves into Aug = [quad + trv*I | HUW] ----
    // qacc = (accA.x + accB.y, accB.x - accA.y)
    if (half == 0) {
        #pragma unroll
        for (int i = 0; i < 4; ++i)
            #pragma unroll
            for (int j = 0; j < 4; ++j) {
                float2 v = make_float2(accA[i][j].x + accB[i][j].y,
                                       accB[i][j].x - accA[i][j].y);
                int row = a + 16 * i, col = bb + 16 * j;
                if (row == col) { v.x += trv.x; v.y += trv.y; }
                sh.Aug[row][col] = v;
            }
        #pragma unroll
        for (int e = 0; e < 2; ++e)
            #pragma unroll
            for (int jj = 0; jj < 2; ++jj)
                sh.Aug[t4][64 + e * 8 + kkb + jj] = huw[e * 2 + jj];
    }
    __syncthreads();
    if (half == 1) {
        #pragma unroll
        for (int i = 0; i < 4; ++i)
            #pragma unroll
            for (int j = 0; j < 4; ++j) {
                int row = a + 16 * i, col = bb + 16 * j;
                float2 v = sh.Aug[row][col];
                v.x += accA[i][j].x + accB[i][j].y;
                v.y += accB[i][j].x - accA[i][j].y;
                sh.Aug[row][col] = v;
            }
        #pragma unroll
        for (int e = 0; e < 2; ++e)
            #pragma unroll
            for (int jj = 0; jj < 2; ++jj) {
                int col = 64 + e * 8 + kkb + jj;
                float2 v = sh.Aug[t4][col];
                v.x += huw[e * 2 + jj].x; v.y += huw[e * 2 + jj].y;
                sh.Aug[t4][col] = v;
            }
    }
    __syncthreads();

    // ---- panel Gauss-Jordan: 8 chunks of 8 pivots, wave-local cascades ----
    const int gi = tid >> 3, gc = tid & 7;           // row 0..63, col-slice 0..7
    const int cb = 10 * gc;                          // 10 cols per thread
    const int lanebase = (tid & 63) & 56;            // my row's base lane

    float2 xr[10];
    {
        const float4* rp = (const float4*)&sh.Aug[gi][cb];
        float4 q0 = rp[0], q1 = rp[1], q2 = rp[2], q3 = rp[3], q4 = rp[4];
        xr[0] = make_float2(q0.x, q0.y); xr[1] = make_float2(q0.z, q0.w);
        xr[2] = make_float2(q1.x, q1.y); xr[3] = make_float2(q1.z, q1.w);
        xr[4] = make_float2(q2.x, q2.y); xr[5] = make_float2(q2.z, q2.w);
        xr[6] = make_float2(q3.x, q3.y); xr[7] = make_float2(q3.z, q3.w);
        xr[8] = make_float2(q4.x, q4.y); xr[9] = make_float2(q4.z, q4.w);
    }

    float2 myipv = make_float2(0.f, 0.f);

    // wave-local cascade: in-panel GJ on my wave's 8 rows, publish to buf nb
    auto cascade = [&](int chunk, int nb) {
        #pragma unroll
        for (int p = 0; p < 8; ++p) {
            const int col = 8 * chunk + p;
            const int cs  = col / 10;                // owning col-slice
            float2 cand = make_float2(0.f, 0.f);
            #pragma unroll
            for (int c = 0; c < 10; ++c)
                if (cb + c == col) cand = xr[c];
            float2 z, Lv;
            z.x  = __shfl(cand.x, p * 8 + cs);
            z.y  = __shfl(cand.y, p * 8 + cs);
            Lv.x = __shfl(cand.x, lanebase + cs);
            Lv.y = __shfl(cand.y, lanebase + cs);
            float  zi  = 1.0f / (z.x * z.x + z.y * z.y);
            float2 ipv = make_float2(z.x * zi, -z.y * zi);
            const bool isPiv = (gi == col);
            if (isPiv) myipv = ipv;
            float2 pr[10];
            #pragma unroll
            for (int c = 0; c < 10; ++c) {
                pr[c].x = __shfl(xr[c].x, p * 8 + gc);
                pr[c].y = __shfl(xr[c].y, p * 8 + gc);
            }
            if (!isPiv) {
                float2 L = cmul(Lv, ipv);
                #pragma unroll
                for (int c = 0; c < 10; ++c) {
                    xr[c].x -= L.x * pr[c].x - L.y * pr[c].y;
                    xr[c].y -= L.x * pr[c].y + L.y * pr[c].x;
                }
            }
        }
        // publish raw pivot rows + inverse pivots
        const int prw = gi & 7;
        float4* wp = (float4*)&shc.gj.pivR[nb][prw][cb];
        wp[0] = make_float4(xr[0].x, xr[0].y, xr[1].x, xr[1].y);
        wp[1] = make_float4(xr[2].x, xr[2].y, xr[3].x, xr[3].y);
        wp[2] = make_float4(xr[4].x, xr[4].y, xr[5].x, xr[5].y);
        wp[3] = make_float4(xr[6].x, xr[6].y, xr[7].x, xr[7].y);
        wp[4] = make_float4(xr[8].x, xr[8].y, xr[9].x, xr[9].y);
        if (gc == 0) shc.gj.pivI[nb][prw] = myipv;
    };

    // eliminate the 8 published pivots of `chunk` (buf bf) from my row.
    auto eliminate = [&](int chunk, int bf) {
        #pragma unroll
        for (int p = 0; p < 8; ++p) {
            const int col = 8 * chunk + p;
            float2 cand = make_float2(0.f, 0.f);
            #pragma unroll
            for (int c = 0; c < 10; ++c)
                if (cb + c == col) cand = xr[c];
            float2 Lv;
            Lv.x = __shfl(cand.x, lanebase + col / 10);
            Lv.y = __shfl(cand.y, lanebase + col / 10);
            float2 ipv = shc.gj.pivI[bf][p];
            float2 L = cmul(Lv, ipv);
            const float4* pp = (const float4*)&shc.gj.pivR[bf][p][cb];
            float4 p0 = pp[0], p1 = pp[1], p2 = pp[2], p3 = pp[3], p4 = pp[4];
            float2 pr[10];
            pr[0] = make_float2(p0.x, p0.y); pr[1] = make_float2(p0.z, p0.w);
            pr[2] = make_float2(p1.x, p1.y); pr[3] = make_float2(p1.z, p1.w);
            pr[4] = make_float2(p2.x, p2.y); pr[5] = make_float2(p2.z, p2.w);
            pr[6] = make_float2(p3.x, p3.y); pr[7] = make_float2(p3.z, p3.w);
            pr[8] = make_float2(p4.x, p4.y); pr[9] = make_float2(p4.z, p4.w);
            #pragma unroll
            for (int c = 0; c < 10; ++c) {
                xr[c].x -= L.x * pr[c].x - L.y * pr[c].y;
                xr[c].y -= L.x * pr[c].y + L.y * pr[c].x;
            }
        }
    };

    int cur = 0;
    if (wv == 0) cascade(0, 0);
    __syncthreads();

    #pragma unroll 1
    for (int c = 0; c < 8; ++c) {
        if (wv != c) {
            eliminate(c, cur);
            if (wv == c + 1) cascade(c + 1, cur ^ 1);
        }
        __syncthreads();
        cur ^= 1;
    }

    // ---- extract solution (cols 64..79), normalize, write ----
    float ss = 0.f;
    if (gc == 6) {
        #pragma unroll
        for (int c = 4; c < 10; ++c) {
            float2 xv = cmul(xr[c], myipv);
            ss += xv.x * xv.x + xv.y * xv.y;
            sv.xout[gi][c - 4] = xv;
        }
    } else if (gc == 7) {
        #pragma unroll
        for (int c = 0; c < 10; ++c) {
            float2 xv = cmul(xr[c], myipv);
            ss += xv.x * xv.x + xv.y * xv.y;
            sv.xout[gi][6 + c] = xv;
        }
    }
    #pragma unroll
    for (int off = 32; off; off >>= 1) ss += __shfl_xor(ss, off);
    if ((tid & 63) == 0) fred[wv] = ss;
    __syncthreads();
    float total = 0.f;
    #pragma unroll
    for (int w = 0; w < 8; ++w) total += fred[w];
    float invn = rsqrtf(total);
    #pragma unroll
    for (int q = 0; q < 2; ++q) {
        int m = tid + q * 512;
        float2 v = sv.xout[m >> 4][m & 15];
        out[(size_t)b * 1024 + m] = make_float2(v.x * invn, v.y * invn);
    }
}

extern "C" void kernel_launch(void* const* d_in, const int* in_sizes, int n_in,
                              void* d_out, int out_size, void* d_ws, size_t ws_size,
                              hipStream_t stream) {
    const float* channel    = (const float*)d_in[0];
    const float* prediction = (const float*)d_in[1];
    int batch = in_sizes[0] / 65536;   // 256
    uw2v_kernel<<<dim3(batch), dim3(512), 0, stream>>>(channel, prediction,
                                                       (float2*)d_out);
}

// Round 11
// 154.962 us; speedup vs baseline: 3.0671x; 1.0772x over previous
//
#include <hip/hip_runtime.h>
#include <math.h>

// NT=64, NR=4, DK=2, KU=8, BR=16, BATCH=256
// channel:    [B][64][4][16][16] f32 (last dim: 8 re, 8 im)
// prediction: [B][2560] = U[4][2][16][16] ++ W[2][2][16][8]
// out:        [B][64][2][8][2] f32
//
// R19 = R15 (88us: R8 quad + 8-pivot panel GJ) + packed-fp32 math:
//  - accA/accB become ext_vector float2 (v2f); quad inner loop written as
//    splat(tq.c) * hq-pair via __builtin_elementwise_fma -> clang selects
//    v_pk_fma_f32 (VOP3P, 2 FMA/instr on gfx90a+/gfx950). 1024 fmaf ->
//    512 pk-fma per thread per fi. Worst case ISel falls back to 2x
//    v_fma_f32 = exactly today's code (bounded downside).
//  - same for GJ eliminate/cascade row updates: xr -= L*pr (complex) as
//    fma(splat(-L.x), pr, fma({L.y,-L.y}, swap(pr), xr)).
// R18's global_load_lds prefetch was neutral (gather latency not the
// bottleneck) -> dropped; plain __syncthreads base kept for simplicity.

#define SAUG 84   // float2 stride of Aug rows
#define STP  65   // float4 stride of paired TtP/HtP rows

typedef float v2f __attribute__((ext_vector_type(2)));

namespace {
union alignas(16) ShU {
    struct { float4 TtP[2][2][8][STP]; float4 HtP[2][2][8][STP]; } p1; // 66560 B
    float2 Aug[64][SAUG];                                              // 43008 B
};
union alignas(16) ShV {
    struct { float2 U[4 * 258]; float W[512]; } in;                    // 10304 B
    float2 xout[64][17];                                               // 8704 B
};
}

__device__ __forceinline__ float2 cmul(float2 x, float2 y) {
    return make_float2(x.x * y.x - x.y * y.y, x.x * y.y + x.y * y.x);
}
__device__ __forceinline__ v2f s2(float s) { return (v2f){s, s}; }

__global__ __launch_bounds__(512, 1)
void uw2v_kernel(const float* __restrict__ channel,
                 const float* __restrict__ prediction,
                 float2* __restrict__ out)
{
    __shared__ ShU sh;
    __shared__ ShV sv;
    __shared__ alignas(16) float2 pivR[2][8][80];  // chunk pivot rows (dbuf)
    __shared__ float2 pivI[2][8];                  // chunk inverse pivots
    __shared__ float2 redbuf[8];
    __shared__ float  fred[8];

    const int b   = blockIdx.x;
    const int tid = threadIdx.x;
    const int wv  = tid >> 6;
    const float* pred = prediction + (size_t)b * 2560;
    const float* chan = channel + (size_t)b * 65536;

    // ---- load U (re/im merged, padded per-r stride) and W ----
    #pragma unroll
    for (int i = 0; i < 2; ++i) {
        int m = tid + i * 512;                       // [r][d][f][k]
        int r = m >> 8, d = (m >> 7) & 1, f = (m >> 3) & 15, k = m & 7;
        const float* src = pred + (((r * 2 + d) * 16 + f) << 4);
        sv.in.U[r * 258 + ((d * 16 + f) << 3) + k] = make_float2(src[k], src[k + 8]);
    }
    sv.in.W[tid] = pred[2048 + tid];
    __syncthreads();

    const int half = tid >> 8;
    const int lt   = tid & 255;
    const int t4 = lt >> 2, r4 = lt & 3;
    const int a  = lt >> 4, bb = lt & 15;
    const int bit0 = r4 & 1, bit1 = (r4 >> 1) & 1;
    const int kkb  = 4 * bit0 + 2 * bit1;            // owned k-slice base (even)
    const int mpb  = kkb >> 1;                       // owned m-pair row (0..3)
    const int fbase = half << 3;
    const int tr_r = lt >> 5, tr_d = (lt >> 4) & 1, tr_e = (lt >> 3) & 1, tr_k = lt & 7;

    // split accumulators (v2f pairs): accA = sum t_re*h, accB = sum t_im*h
    v2f accA[4][4], accB[4][4];
    #pragma unroll
    for (int i = 0; i < 4; ++i)
        #pragma unroll
        for (int j = 0; j < 4; ++j) {
            accA[i][j] = (v2f){0.f, 0.f};
            accB[i][j] = (v2f){0.f, 0.f};
        }
    float2 huw[4] = {make_float2(0,0), make_float2(0,0), make_float2(0,0), make_float2(0,0)};
    float2 tracc  = make_float2(0.f, 0.f);

    const float* hbase = chan + ((t4 * 4 + r4) << 8) + (fbase << 4);

    #pragma unroll 1
    for (int fi = 0; fi < 8; ++fi) {
        const int f = fbase + fi;
        const float4 ca = *(const float4*)(hbase + (fi << 4) + 0);
        const float4 cb = *(const float4*)(hbase + (fi << 4) + 4);
        const float4 ci = *(const float4*)(hbase + (fi << 4) + 8);
        const float4 cd = *(const float4*)(hbase + (fi << 4) + 12);

        const float4* U0p = (const float4*)&sv.in.U[r4 * 258 + (f << 3)];        // d=0
        const float4* U1p = (const float4*)&sv.in.U[r4 * 258 + ((16 + f) << 3)]; // d=1
        const float4 u0q0 = U0p[0], u0q1 = U0p[1], u0q2 = U0p[2], u0q3 = U0p[3];
        const float4 u1q0 = U1p[0], u1q1 = U1p[1], u1q2 = U1p[2], u1q3 = U1p[3];

        // partials: val0[k] = conj(H)*U (d=0, m=k), val1[k] (d=1, m=8+k)
        float2 val0[8], val1[8];
        #define MK2(K, HR, HI, U0R, U0I, U1R, U1I) \
            val0[K] = make_float2((HR)*(U0R) + (HI)*(U0I), (HR)*(U0I) - (HI)*(U0R)); \
            val1[K] = make_float2((HR)*(U1R) + (HI)*(U1I), (HR)*(U1I) - (HI)*(U1R));
        MK2(0, ca.x, ci.x, u0q0.x, u0q0.y, u1q0.x, u1q0.y)
        MK2(1, ca.y, ci.y, u0q0.z, u0q0.w, u1q0.z, u1q0.w)
        MK2(2, ca.z, ci.z, u0q1.x, u0q1.y, u1q1.x, u1q1.y)
        MK2(3, ca.w, ci.w, u0q1.z, u0q1.w, u1q1.z, u1q1.w)
        MK2(4, cb.x, cd.x, u0q2.x, u0q2.y, u1q2.x, u1q2.y)
        MK2(5, cb.y, cd.y, u0q2.z, u0q2.w, u1q2.z, u1q2.w)
        MK2(6, cb.z, cd.z, u0q3.x, u0q3.y, u1q3.x, u1q3.y)
        MK2(7, cb.w, cd.w, u0q3.z, u0q3.w, u1q3.z, u1q3.w)
        #undef MK2

        // stage 1 (xor 1): keep k in {4*bit0 .. 4*bit0+3}
        float2 s1d0[4], s1d1[4];
        #pragma unroll
        for (int q = 0; q < 4; ++q) {
            float2 k0 = bit0 ? val0[4 + q] : val0[q];
            float2 n0 = bit0 ? val0[q]     : val0[4 + q];
            float2 k1 = bit0 ? val1[4 + q] : val1[q];
            float2 n1 = bit0 ? val1[q]     : val1[4 + q];
            n0.x = __shfl_xor(n0.x, 1); n0.y = __shfl_xor(n0.y, 1);
            n1.x = __shfl_xor(n1.x, 1); n1.y = __shfl_xor(n1.y, 1);
            s1d0[q] = make_float2(k0.x + n0.x, k0.y + n0.y);
            s1d1[q] = make_float2(k1.x + n1.x, k1.y + n1.y);
        }
        // stage 2 (xor 2): keep q in {2*bit1, 2*bit1+1} -> hh[kkb+jj]
        float2 h0[2], h1[2];
        #pragma unroll
        for (int jj = 0; jj < 2; ++jj) {
            float2 k0 = bit1 ? s1d0[2 + jj] : s1d0[jj];
            float2 n0 = bit1 ? s1d0[jj]     : s1d0[2 + jj];
            float2 k1 = bit1 ? s1d1[2 + jj] : s1d1[jj];
            float2 n1 = bit1 ? s1d1[jj]     : s1d1[2 + jj];
            n0.x = __shfl_xor(n0.x, 2); n0.y = __shfl_xor(n0.y, 2);
            n1.x = __shfl_xor(n1.x, 2); n1.y = __shfl_xor(n1.y, 2);
            h0[jj] = make_float2(k0.x + n0.x, k0.y + n0.y);
            h1[jj] = make_float2(k1.x + n1.x, k1.y + n1.y);
        }

        // tr_UWU partial (128 lanes per half; wave-uniform branch)
        if (lt < 128) {
            float w   = sv.in.W[((tr_d * 2 + tr_e) * 16 + f) * 8 + tr_k];
            float2 u1 = sv.in.U[tr_r * 258 + ((tr_d * 16 + f) << 3) + tr_k];
            float2 u2 = sv.in.U[tr_r * 258 + ((tr_e * 16 + f) << 3) + tr_k];
            tracc.x += w * (u1.x * u2.x + u1.y * u2.y);
            tracc.y += w * (u1.y * u2.x - u1.x * u2.y);
        }

        // T pairs + H pairs (b128 writes, m-pair rows)
        const int p = fi & 1;
        #pragma unroll
        for (int e = 0; e < 2; ++e) {
            float w0a = sv.in.W[(e * 16 + f) * 8 + kkb];
            float w0b = sv.in.W[(e * 16 + f) * 8 + kkb + 1];
            float w1a = sv.in.W[((2 + e) * 16 + f) * 8 + kkb];
            float w1b = sv.in.W[((2 + e) * 16 + f) * 8 + kkb + 1];
            float2 tva = make_float2(h0[0].x * w0a + h1[0].x * w1a,
                                     h0[0].y * w0a + h1[0].y * w1a);
            float2 tvb = make_float2(h0[1].x * w0b + h1[1].x * w1b,
                                     h0[1].y * w0b + h1[1].y * w1b);
            sh.p1.TtP[p][half][e * 4 + mpb][t4] = make_float4(tva.x, tva.y, tvb.x, tvb.y);
            huw[e * 2 + 0].x += tva.x; huw[e * 2 + 0].y += tva.y;
            huw[e * 2 + 1].x += tvb.x; huw[e * 2 + 1].y += tvb.y;
        }
        sh.p1.HtP[p][half][mpb][t4]     = make_float4(h0[0].x, h0[0].y, h0[1].x, h0[1].y);
        sh.p1.HtP[p][half][4 + mpb][t4] = make_float4(h1[0].x, h1[0].y, h1[1].x, h1[1].y);
        __syncthreads();

        // quad: packed-pair accumulation over m-pairs (v_pk_fma_f32)
        #pragma unroll
        for (int mp = 0; mp < 8; ++mp) {
            float4 tq[4], hq[4];
            #pragma unroll
            for (int i = 0; i < 4; ++i) tq[i] = sh.p1.TtP[p][half][mp][a + 16 * i];
            #pragma unroll
            for (int j = 0; j < 4; ++j) hq[j] = sh.p1.HtP[p][half][mp][bb + 16 * j];
            #pragma unroll
            for (int i = 0; i < 4; ++i)
                #pragma unroll
                for (int j = 0; j < 4; ++j) {
                    v2f hq01 = (v2f){hq[j].x, hq[j].y};
                    v2f hq23 = (v2f){hq[j].z, hq[j].w};
                    v2f va = accA[i][j], vb = accB[i][j];
                    va = __builtin_elementwise_fma(s2(tq[i].x), hq01, va);
                    va = __builtin_elementwise_fma(s2(tq[i].z), hq23, va);
                    vb = __builtin_elementwise_fma(s2(tq[i].y), hq01, vb);
                    vb = __builtin_elementwise_fma(s2(tq[i].w), hq23, vb);
                    accA[i][j] = va; accB[i][j] = vb;
                }
        }
    }

    // ---- tr_UWU block reduction ----
    #pragma unroll
    for (int off = 32; off; off >>= 1) {
        tracc.x += __shfl_xor(tracc.x, off);
        tracc.y += __shfl_xor(tracc.y, off);
    }
    if ((tid & 63) == 0) redbuf[wv] = tracc;
    __syncthreads();
    float2 trv = make_float2(0.f, 0.f);
    #pragma unroll
    for (int w = 0; w < 8; ++w) { trv.x += redbuf[w].x; trv.y += redbuf[w].y; }
    trv.x *= 0.1f; trv.y *= 0.1f;

    // ---- merge halves into Aug = [quad + trv*I | HUW] ----
    // qacc = (accA.x + accB.y, accB.x - accA.y)
    if (half == 0) {
        #pragma unroll
        for (int i = 0; i < 4; ++i)
            #pragma unroll
            for (int j = 0; j < 4; ++j) {
                float2 v = make_float2(accA[i][j].x + accB[i][j].y,
                                       accB[i][j].x - accA[i][j].y);
                int row = a + 16 * i, col = bb + 16 * j;
                if (row == col) { v.x += trv.x; v.y += trv.y; }
                sh.Aug[row][col] = v;
            }
        #pragma unroll
        for (int e = 0; e < 2; ++e)
            #pragma unroll
            for (int jj = 0; jj < 2; ++jj)
                sh.Aug[t4][64 + e * 8 + kkb + jj] = huw[e * 2 + jj];
    }
    __syncthreads();
    if (half == 1) {
        #pragma unroll
        for (int i = 0; i < 4; ++i)
            #pragma unroll
            for (int j = 0; j < 4; ++j) {
                int row = a + 16 * i, col = bb + 16 * j;
                float2 v = sh.Aug[row][col];
                v.x += accA[i][j].x + accB[i][j].y;
                v.y += accB[i][j].x - accA[i][j].y;
                sh.Aug[row][col] = v;
            }
        #pragma unroll
        for (int e = 0; e < 2; ++e)
            #pragma unroll
            for (int jj = 0; jj < 2; ++jj) {
                int col = 64 + e * 8 + kkb + jj;
                float2 v = sh.Aug[t4][col];
                v.x += huw[e * 2 + jj].x; v.y += huw[e * 2 + jj].y;
                sh.Aug[t4][col] = v;
            }
    }
    __syncthreads();

    // ---- panel Gauss-Jordan: 8 chunks of 8 pivots, wave-local cascades ----
    const int gi = tid >> 3, gc = tid & 7;           // row 0..63, col-slice 0..7
    const int cb = 10 * gc;                          // 10 cols per thread
    const int lanebase = (tid & 63) & 56;            // my row's base lane

    v2f xr[10];
    {
        const float4* rp = (const float4*)&sh.Aug[gi][cb];
        float4 q0 = rp[0], q1 = rp[1], q2 = rp[2], q3 = rp[3], q4 = rp[4];
        xr[0] = (v2f){q0.x, q0.y}; xr[1] = (v2f){q0.z, q0.w};
        xr[2] = (v2f){q1.x, q1.y}; xr[3] = (v2f){q1.z, q1.w};
        xr[4] = (v2f){q2.x, q2.y}; xr[5] = (v2f){q2.z, q2.w};
        xr[6] = (v2f){q3.x, q3.y}; xr[7] = (v2f){q3.z, q3.w};
        xr[8] = (v2f){q4.x, q4.y}; xr[9] = (v2f){q4.z, q4.w};
    }

    float2 myipv = make_float2(0.f, 0.f);

    // packed complex row update: xr -= L * pr (pr as v2f pair)
    // xr = fma(splat(-L.x), pr, fma({L.y,-L.y}, swap(pr), xr))
    auto rowupd = [](v2f* xr10, const v2f* pr10, float2 L) {
        v2f nLx = s2(-L.x);
        v2f Lyp = (v2f){L.y, -L.y};
        #pragma unroll
        for (int c = 0; c < 10; ++c) {
            v2f prv = pr10[c];
            v2f prsw = (v2f){prv.y, prv.x};
            xr10[c] = __builtin_elementwise_fma(
                nLx, prv, __builtin_elementwise_fma(Lyp, prsw, xr10[c]));
        }
    };

    // wave-local cascade: in-panel GJ on my wave's 8 rows, publish to buf nb
    auto cascade = [&](int chunk, int nb) {
        #pragma unroll
        for (int p = 0; p < 8; ++p) {
            const int col = 8 * chunk + p;
            const int cs  = col / 10;                // owning col-slice
            float2 cand = make_float2(0.f, 0.f);
            #pragma unroll
            for (int c = 0; c < 10; ++c)
                if (cb + c == col) cand = make_float2(xr[c].x, xr[c].y);
            float2 z, Lv;
            z.x  = __shfl(cand.x, p * 8 + cs);
            z.y  = __shfl(cand.y, p * 8 + cs);
            Lv.x = __shfl(cand.x, lanebase + cs);
            Lv.y = __shfl(cand.y, lanebase + cs);
            float  zi  = 1.0f / (z.x * z.x + z.y * z.y);
            float2 ipv = make_float2(z.x * zi, -z.y * zi);
            const bool isPiv = (gi == col);
            if (isPiv) myipv = ipv;
            v2f pr[10];
            #pragma unroll
            for (int c = 0; c < 10; ++c) {
                pr[c].x = __shfl(xr[c].x, p * 8 + gc);
                pr[c].y = __shfl(xr[c].y, p * 8 + gc);
            }
            if (!isPiv) {
                float2 L = cmul(Lv, ipv);
                rowupd(xr, pr, L);
            }
        }
        // publish raw pivot rows + inverse pivots
        const int prw = gi & 7;
        float4* wp = (float4*)&pivR[nb][prw][cb];
        wp[0] = make_float4(xr[0].x, xr[0].y, xr[1].x, xr[1].y);
        wp[1] = make_float4(xr[2].x, xr[2].y, xr[3].x, xr[3].y);
        wp[2] = make_float4(xr[4].x, xr[4].y, xr[5].x, xr[5].y);
        wp[3] = make_float4(xr[6].x, xr[6].y, xr[7].x, xr[7].y);
        wp[4] = make_float4(xr[8].x, xr[8].y, xr[9].x, xr[9].y);
        if (gc == 0) pivI[nb][prw] = myipv;
    };

    // eliminate the 8 published pivots of `chunk` (buf bf) from my row.
    auto eliminate = [&](int chunk, int bf) {
        #pragma unroll
        for (int p = 0; p < 8; ++p) {
            const int col = 8 * chunk + p;
            float2 cand = make_float2(0.f, 0.f);
            #pragma unroll
            for (int c = 0; c < 10; ++c)
                if (cb + c == col) cand = make_float2(xr[c].x, xr[c].y);
            float2 Lv;
            Lv.x = __shfl(cand.x, lanebase + col / 10);
            Lv.y = __shfl(cand.y, lanebase + col / 10);
            float2 ipv = pivI[bf][p];
            float2 L = cmul(Lv, ipv);
            const float4* pp = (const float4*)&pivR[bf][p][cb];
            float4 p0 = pp[0], p1 = pp[1], p2 = pp[2], p3 = pp[3], p4 = pp[4];
            v2f pr[10];
            pr[0] = (v2f){p0.x, p0.y}; pr[1] = (v2f){p0.z, p0.w};
            pr[2] = (v2f){p1.x, p1.y}; pr[3] = (v2f){p1.z, p1.w};
            pr[4] = (v2f){p2.x, p2.y}; pr[5] = (v2f){p2.z, p2.w};
            pr[6] = (v2f){p3.x, p3.y}; pr[7] = (v2f){p3.z, p3.w};
            pr[8] = (v2f){p4.x, p4.y}; pr[9] = (v2f){p4.z, p4.w};
            rowupd(xr, pr, L);
        }
    };

    int cur = 0;
    if (wv == 0) cascade(0, 0);
    __syncthreads();

    #pragma unroll 1
    for (int c = 0; c < 8; ++c) {
        if (wv != c) {
            eliminate(c, cur);
            if (wv == c + 1) cascade(c + 1, cur ^ 1);
        }
        __syncthreads();
        cur ^= 1;
    }

    // ---- extract solution (cols 64..79), normalize, write ----
    float ss = 0.f;
    if (gc == 6) {
        #pragma unroll
        for (int c = 4; c < 10; ++c) {
            float2 xv = cmul(make_float2(xr[c].x, xr[c].y), myipv);
            ss += xv.x * xv.x + xv.y * xv.y;
            sv.xout[gi][c - 4] = xv;
        }
    } else if (gc == 7) {
        #pragma unroll
        for (int c = 0; c < 10; ++c) {
            float2 xv = cmul(make_float2(xr[c].x, xr[c].y), myipv);
            ss += xv.x * xv.x + xv.y * xv.y;
            sv.xout[gi][6 + c] = xv;
        }
    }
    #pragma unroll
    for (int off = 32; off; off >>= 1) ss += __shfl_xor(ss, off);
    if ((tid & 63) == 0) fred[wv] = ss;
    __syncthreads();
    float total = 0.f;
    #pragma unroll
    for (int w = 0; w < 8; ++w) total += fred[w];
    float invn = rsqrtf(total);
    #pragma unroll
    for (int q = 0; q < 2; ++q) {
        int m = tid + q * 512;
        float2 v = sv.xout[m >> 4][m & 15];
        out[(size_t)b * 1024 + m] = make_float2(v.x * invn, v.y * invn);
    }
}

extern "C" void kernel_launch(void* const* d_in, const int* in_sizes, int n_in,
                              void* d_out, int out_size, void* d_ws, size_t ws_size,
                              hipStream_t stream) {
    const float* channel    = (const float*)d_in[0];
    const float* prediction = (const float*)d_in[1];
    int batch = in_sizes[0] / 65536;   // 256
    uw2v_kernel<<<dim3(batch), dim3(512), 0, stream>>>(channel, prediction,
                                                       (float2*)d_out);
}

// Round 13
// 151.859 us; speedup vs baseline: 3.1298x; 1.0204x over previous
//
#include <hip/hip_runtime.h>
#include <math.h>

// NT=64, NR=4, DK=2, KU=8, BR=16, BATCH=256
// channel:    [B][64][4][16][16] f32 (last dim: 8 re, 8 im)
// prediction: [B][2560] = U[4][2][16][16] ++ W[2][2][16][8]
// out:        [B][64][2][8][2] f32
//
// R21 = R20 resubmitted verbatim (previous round died on container
// acquisition, not on the kernel: no compile error / no result data).
// R20 = R19 (155us harness: pk-fma quad + 8-pivot panel GJ) with the
// shfl butterfly ELIMINATED. DS-pipe census showed the quad loop issues
// ~888 DS ops/CU/fi (quad reads 512, butterfly shfls 192, U 64, W/tr 88,
// writes 32) and is DS-throughput/latency bound (VALUBusy only 26%).
// Change: thread remap (t4, r4) -> (t4, kq). Each thread owns k-pair
// {2kq, 2kq+1} and reduces over r LOCALLY by reading all 4 channel rows
// itself (8x8B global loads - idle VMEM pipe, L2-resident data) instead
// of 4-lane shfl_xor reduction. Zero shfls; W reads 8xb32 -> 4xb64.
// T/H tile layout unchanged (kk0=2kq; row e*4+kq covers rows 0..3 same
// as old permuted mpb), so quad, merge, GJ, epilogue are untouched.
// DS ops/fi: 888 -> ~660.

#define SAUG 84   // float2 stride of Aug rows
#define STP  65   // float4 stride of paired TtP/HtP rows

typedef float v2f __attribute__((ext_vector_type(2)));

namespace {
union alignas(16) ShU {
    struct { float4 TtP[2][2][8][STP]; float4 HtP[2][2][8][STP]; } p1; // 66560 B
    float2 Aug[64][SAUG];                                              // 43008 B
};
union alignas(16) ShV {
    struct { float2 U[4 * 258]; float W[512]; } in;                    // 10304 B
    float2 xout[64][17];                                               // 8704 B
};
}

__device__ __forceinline__ float2 cmul(float2 x, float2 y) {
    return make_float2(x.x * y.x - x.y * y.y, x.x * y.y + x.y * y.x);
}
__device__ __forceinline__ v2f s2(float s) { return (v2f){s, s}; }

__global__ __launch_bounds__(512, 1)
void uw2v_kernel(const float* __restrict__ channel,
                 const float* __restrict__ prediction,
                 float2* __restrict__ out)
{
    __shared__ ShU sh;
    __shared__ ShV sv;
    __shared__ alignas(16) float2 pivR[2][8][80];  // chunk pivot rows (dbuf)
    __shared__ float2 pivI[2][8];                  // chunk inverse pivots
    __shared__ float2 redbuf[8];
    __shared__ float  fred[8];

    const int b   = blockIdx.x;
    const int tid = threadIdx.x;
    const int wv  = tid >> 6;
    const float* pred = prediction + (size_t)b * 2560;
    const float* chan = channel + (size_t)b * 65536;

    // ---- load U (re/im merged, padded per-r stride) and W ----
    #pragma unroll
    for (int i = 0; i < 2; ++i) {
        int m = tid + i * 512;                       // [r][d][f][k]
        int r = m >> 8, d = (m >> 7) & 1, f = (m >> 3) & 15, k = m & 7;
        const float* src = pred + (((r * 2 + d) * 16 + f) << 4);
        sv.in.U[r * 258 + ((d * 16 + f) << 3) + k] = make_float2(src[k], src[k + 8]);
    }
    sv.in.W[tid] = pred[2048 + tid];
    __syncthreads();

    const int half = tid >> 8;
    const int lt   = tid & 255;
    const int t4 = lt >> 2, kq = lt & 3;             // row, owned k-pair index
    const int a  = lt >> 4, bb = lt & 15;
    const int kk0 = 2 * kq;                          // owned k-slice base (even)
    const int fbase = half << 3;
    const int tr_r = lt >> 5, tr_d = (lt >> 4) & 1, tr_e = (lt >> 3) & 1, tr_k = lt & 7;

    // split accumulators (v2f pairs): accA = sum t_re*h, accB = sum t_im*h
    v2f accA[4][4], accB[4][4];
    #pragma unroll
    for (int i = 0; i < 4; ++i)
        #pragma unroll
        for (int j = 0; j < 4; ++j) {
            accA[i][j] = (v2f){0.f, 0.f};
            accB[i][j] = (v2f){0.f, 0.f};
        }
    float2 huw[4] = {make_float2(0,0), make_float2(0,0), make_float2(0,0), make_float2(0,0)};
    float2 tracc  = make_float2(0.f, 0.f);

    // this thread reads all 4 receive rows of its transmit antenna t4
    const float* chanT = chan + ((t4 * 4) << 8) + (fbase << 4);

    #pragma unroll 1
    for (int fi = 0; fi < 8; ++fi) {
        const int f = fbase + fi;

        // H rows r=0..3 at owned k-pair: re pair + im pair (8B loads, VMEM)
        const float* cb0 = chanT + (fi << 4);
        float2 hre[4], him[4];
        #pragma unroll
        for (int r = 0; r < 4; ++r) {
            const float* rp = cb0 + (r << 8);
            hre[r] = *(const float2*)(rp + kk0);
            him[r] = *(const float2*)(rp + 8 + kk0);
        }

        // hh[d][j] = sum_r conj(H[r][t4][f][kk0+j]) * U[r][d][f][kk0+j]
        float2 hh[2][2] = {{make_float2(0,0), make_float2(0,0)},
                           {make_float2(0,0), make_float2(0,0)}};
        #pragma unroll
        for (int r = 0; r < 4; ++r) {
            #pragma unroll
            for (int d = 0; d < 2; ++d) {
                const float4 u = *(const float4*)&sv.in.U[r * 258 + ((d * 16 + f) << 3) + kk0];
                hh[d][0].x += hre[r].x * u.x + him[r].x * u.y;
                hh[d][0].y += hre[r].x * u.y - him[r].x * u.x;
                hh[d][1].x += hre[r].y * u.z + him[r].y * u.w;
                hh[d][1].y += hre[r].y * u.w - him[r].y * u.z;
            }
        }

        // tr_UWU partial (128 lanes per half; wave-uniform branch)
        if (lt < 128) {
            float w   = sv.in.W[((tr_d * 2 + tr_e) * 16 + f) * 8 + tr_k];
            float2 u1 = sv.in.U[tr_r * 258 + ((tr_d * 16 + f) << 3) + tr_k];
            float2 u2 = sv.in.U[tr_r * 258 + ((tr_e * 16 + f) << 3) + tr_k];
            tracc.x += w * (u1.x * u2.x + u1.y * u2.y);
            tracc.y += w * (u1.y * u2.x - u1.x * u2.y);
        }

        // T pairs + H pairs (b128 writes, m-pair rows)
        const int p = fi & 1;
        #pragma unroll
        for (int e = 0; e < 2; ++e) {
            const float2 w0 = *(const float2*)&sv.in.W[(e * 16 + f) * 8 + kk0];       // d=0
            const float2 w1 = *(const float2*)&sv.in.W[((2 + e) * 16 + f) * 8 + kk0]; // d=1
            float2 tva = make_float2(hh[0][0].x * w0.x + hh[1][0].x * w1.x,
                                     hh[0][0].y * w0.x + hh[1][0].y * w1.x);
            float2 tvb = make_float2(hh[0][1].x * w0.y + hh[1][1].x * w1.y,
                                     hh[0][1].y * w0.y + hh[1][1].y * w1.y);
            sh.p1.TtP[p][half][e * 4 + kq][t4] = make_float4(tva.x, tva.y, tvb.x, tvb.y);
            huw[e * 2 + 0].x += tva.x; huw[e * 2 + 0].y += tva.y;
            huw[e * 2 + 1].x += tvb.x; huw[e * 2 + 1].y += tvb.y;
        }
        sh.p1.HtP[p][half][kq][t4]     = make_float4(hh[0][0].x, hh[0][0].y, hh[0][1].x, hh[0][1].y);
        sh.p1.HtP[p][half][4 + kq][t4] = make_float4(hh[1][0].x, hh[1][0].y, hh[1][1].x, hh[1][1].y);
        __syncthreads();

        // quad: packed-pair accumulation over m-pairs (v_pk_fma_f32)
        #pragma unroll
        for (int mp = 0; mp < 8; ++mp) {
            float4 tq[4], hq[4];
            #pragma unroll
            for (int i = 0; i < 4; ++i) tq[i] = sh.p1.TtP[p][half][mp][a + 16 * i];
            #pragma unroll
            for (int j = 0; j < 4; ++j) hq[j] = sh.p1.HtP[p][half][mp][bb + 16 * j];
            #pragma unroll
            for (int i = 0; i < 4; ++i)
                #pragma unroll
                for (int j = 0; j < 4; ++j) {
                    v2f hq01 = (v2f){hq[j].x, hq[j].y};
                    v2f hq23 = (v2f){hq[j].z, hq[j].w};
                    v2f va = accA[i][j], vb = accB[i][j];
                    va = __builtin_elementwise_fma(s2(tq[i].x), hq01, va);
                    va = __builtin_elementwise_fma(s2(tq[i].z), hq23, va);
                    vb = __builtin_elementwise_fma(s2(tq[i].y), hq01, vb);
                    vb = __builtin_elementwise_fma(s2(tq[i].w), hq23, vb);
                    accA[i][j] = va; accB[i][j] = vb;
                }
        }
    }

    // ---- tr_UWU block reduction ----
    #pragma unroll
    for (int off = 32; off; off >>= 1) {
        tracc.x += __shfl_xor(tracc.x, off);
        tracc.y += __shfl_xor(tracc.y, off);
    }
    if ((tid & 63) == 0) redbuf[wv] = tracc;
    __syncthreads();
    float2 trv = make_float2(0.f, 0.f);
    #pragma unroll
    for (int w = 0; w < 8; ++w) { trv.x += redbuf[w].x; trv.y += redbuf[w].y; }
    trv.x *= 0.1f; trv.y *= 0.1f;

    // ---- merge halves into Aug = [quad + trv*I | HUW] ----
    // qacc = (accA.x + accB.y, accB.x - accA.y)
    if (half == 0) {
        #pragma unroll
        for (int i = 0; i < 4; ++i)
            #pragma unroll
            for (int j = 0; j < 4; ++j) {
                float2 v = make_float2(accA[i][j].x + accB[i][j].y,
                                       accB[i][j].x - accA[i][j].y);
                int row = a + 16 * i, col = bb + 16 * j;
                if (row == col) { v.x += trv.x; v.y += trv.y; }
                sh.Aug[row][col] = v;
            }
        #pragma unroll
        for (int e = 0; e < 2; ++e)
            #pragma unroll
            for (int jj = 0; jj < 2; ++jj)
                sh.Aug[t4][64 + e * 8 + kk0 + jj] = huw[e * 2 + jj];
    }
    __syncthreads();
    if (half == 1) {
        #pragma unroll
        for (int i = 0; i < 4; ++i)
            #pragma unroll
            for (int j = 0; j < 4; ++j) {
                int row = a + 16 * i, col = bb + 16 * j;
                float2 v = sh.Aug[row][col];
                v.x += accA[i][j].x + accB[i][j].y;
                v.y += accB[i][j].x - accA[i][j].y;
                sh.Aug[row][col] = v;
            }
        #pragma unroll
        for (int e = 0; e < 2; ++e)
            #pragma unroll
            for (int jj = 0; jj < 2; ++jj) {
                int col = 64 + e * 8 + kk0 + jj;
                float2 v = sh.Aug[t4][col];
                v.x += huw[e * 2 + jj].x; v.y += huw[e * 2 + jj].y;
                sh.Aug[t4][col] = v;
            }
    }
    __syncthreads();

    // ---- panel Gauss-Jordan: 8 chunks of 8 pivots, wave-local cascades ----
    const int gi = tid >> 3, gc = tid & 7;           // row 0..63, col-slice 0..7
    const int cb = 10 * gc;                          // 10 cols per thread
    const int lanebase = (tid & 63) & 56;            // my row's base lane

    v2f xr[10];
    {
        const float4* rp = (const float4*)&sh.Aug[gi][cb];
        float4 q0 = rp[0], q1 = rp[1], q2 = rp[2], q3 = rp[3], q4 = rp[4];
        xr[0] = (v2f){q0.x, q0.y}; xr[1] = (v2f){q0.z, q0.w};
        xr[2] = (v2f){q1.x, q1.y}; xr[3] = (v2f){q1.z, q1.w};
        xr[4] = (v2f){q2.x, q2.y}; xr[5] = (v2f){q2.z, q2.w};
        xr[6] = (v2f){q3.x, q3.y}; xr[7] = (v2f){q3.z, q3.w};
        xr[8] = (v2f){q4.x, q4.y}; xr[9] = (v2f){q4.z, q4.w};
    }

    float2 myipv = make_float2(0.f, 0.f);

    // packed complex row update: xr -= L * pr (pr as v2f pair)
    auto rowupd = [](v2f* xr10, const v2f* pr10, float2 L) {
        v2f nLx = s2(-L.x);
        v2f Lyp = (v2f){L.y, -L.y};
        #pragma unroll
        for (int c = 0; c < 10; ++c) {
            v2f prv = pr10[c];
            v2f prsw = (v2f){prv.y, prv.x};
            xr10[c] = __builtin_elementwise_fma(
                nLx, prv, __builtin_elementwise_fma(Lyp, prsw, xr10[c]));
        }
    };

    // wave-local cascade: in-panel GJ on my wave's 8 rows, publish to buf nb
    auto cascade = [&](int chunk, int nb) {
        #pragma unroll
        for (int p = 0; p < 8; ++p) {
            const int col = 8 * chunk + p;
            const int cs  = col / 10;                // owning col-slice
            float2 cand = make_float2(0.f, 0.f);
            #pragma unroll
            for (int c = 0; c < 10; ++c)
                if (cb + c == col) cand = make_float2(xr[c].x, xr[c].y);
            float2 z, Lv;
            z.x  = __shfl(cand.x, p * 8 + cs);
            z.y  = __shfl(cand.y, p * 8 + cs);
            Lv.x = __shfl(cand.x, lanebase + cs);
            Lv.y = __shfl(cand.y, lanebase + cs);
            float  zi  = 1.0f / (z.x * z.x + z.y * z.y);
            float2 ipv = make_float2(z.x * zi, -z.y * zi);
            const bool isPiv = (gi == col);
            if (isPiv) myipv = ipv;
            v2f pr[10];
            #pragma unroll
            for (int c = 0; c < 10; ++c) {
                pr[c].x = __shfl(xr[c].x, p * 8 + gc);
                pr[c].y = __shfl(xr[c].y, p * 8 + gc);
            }
            if (!isPiv) {
                float2 L = cmul(Lv, ipv);
                rowupd(xr, pr, L);
            }
        }
        // publish raw pivot rows + inverse pivots
        const int prw = gi & 7;
        float4* wp = (float4*)&pivR[nb][prw][cb];
        wp[0] = make_float4(xr[0].x, xr[0].y, xr[1].x, xr[1].y);
        wp[1] = make_float4(xr[2].x, xr[2].y, xr[3].x, xr[3].y);
        wp[2] = make_float4(xr[4].x, xr[4].y, xr[5].x, xr[5].y);
        wp[3] = make_float4(xr[6].x, xr[6].y, xr[7].x, xr[7].y);
        wp[4] = make_float4(xr[8].x, xr[8].y, xr[9].x, xr[9].y);
        if (gc == 0) pivI[nb][prw] = myipv;
    };

    // eliminate the 8 published pivots of `chunk` (buf bf) from my row.
    auto eliminate = [&](int chunk, int bf) {
        #pragma unroll
        for (int p = 0; p < 8; ++p) {
            const int col = 8 * chunk + p;
            float2 cand = make_float2(0.f, 0.f);
            #pragma unroll
            for (int c = 0; c < 10; ++c)
                if (cb + c == col) cand = make_float2(xr[c].x, xr[c].y);
            float2 Lv;
            Lv.x = __shfl(cand.x, lanebase + col / 10);
            Lv.y = __shfl(cand.y, lanebase + col / 10);
            float2 ipv = pivI[bf][p];
            float2 L = cmul(Lv, ipv);
            const float4* pp = (const float4*)&pivR[bf][p][cb];
            float4 p0 = pp[0], p1 = pp[1], p2 = pp[2], p3 = pp[3], p4 = pp[4];
            v2f pr[10];
            pr[0] = (v2f){p0.x, p0.y}; pr[1] = (v2f){p0.z, p0.w};
            pr[2] = (v2f){p1.x, p1.y}; pr[3] = (v2f){p1.z, p1.w};
            pr[4] = (v2f){p2.x, p2.y}; pr[5] = (v2f){p2.z, p2.w};
            pr[6] = (v2f){p3.x, p3.y}; pr[7] = (v2f){p3.z, p3.w};
            pr[8] = (v2f){p4.x, p4.y}; pr[9] = (v2f){p4.z, p4.w};
            rowupd(xr, pr, L);
        }
    };

    int cur = 0;
    if (wv == 0) cascade(0, 0);
    __syncthreads();

    #pragma unroll 1
    for (int c = 0; c < 8; ++c) {
        if (wv != c) {
            eliminate(c, cur);
            if (wv == c + 1) cascade(c + 1, cur ^ 1);
        }
        __syncthreads();
        cur ^= 1;
    }

    // ---- extract solution (cols 64..79), normalize, write ----
    float ss = 0.f;
    if (gc == 6) {
        #pragma unroll
        for (int c = 4; c < 10; ++c) {
            float2 xv = cmul(make_float2(xr[c].x, xr[c].y), myipv);
            ss += xv.x * xv.x + xv.y * xv.y;
            sv.xout[gi][c - 4] = xv;
        }
    } else if (gc == 7) {
        #pragma unroll
        for (int c = 0; c < 10; ++c) {
            float2 xv = cmul(make_float2(xr[c].x, xr[c].y), myipv);
            ss += xv.x * xv.x + xv.y * xv.y;
            sv.xout[gi][6 + c] = xv;
        }
    }
    #pragma unroll
    for (int off = 32; off; off >>= 1) ss += __shfl_xor(ss, off);
    if ((tid & 63) == 0) fred[wv] = ss;
    __syncthreads();
    float total = 0.f;
    #pragma unroll
    for (int w = 0; w < 8; ++w) total += fred[w];
    float invn = rsqrtf(total);
    #pragma unroll
    for (int q = 0; q < 2; ++q) {
        int m = tid + q * 512;
        float2 v = sv.xout[m >> 4][m & 15];
        out[(size_t)b * 1024 + m] = make_float2(v.x * invn, v.y * invn);
    }
}

extern "C" void kernel_launch(void* const* d_in, const int* in_sizes, int n_in,
                              void* d_out, int out_size, void* d_ws, size_t ws_size,
                              hipStream_t stream) {
    const float* channel    = (const float*)d_in[0];
    const float* prediction = (const float*)d_in[1];
    int batch = in_sizes[0] / 65536;   // 256
    uw2v_kernel<<<dim3(batch), dim3(512), 0, stream>>>(channel, prediction,
                                                       (float2*)d_out);
}